// Round 1
// 228.002 us; speedup vs baseline: 1.0033x; 1.0033x over previous
//
#include <hip/hip_runtime.h>
#include <math.h>

#define NN 4096   // nodes
#define LOG2E 1.44269504088896340736f

using f32x2  = __attribute__((ext_vector_type(2))) float;
using f32x4  = __attribute__((ext_vector_type(4))) float;
using bf16x4 = __attribute__((ext_vector_type(4))) __bf16;
using bf16x8 = __attribute__((ext_vector_type(8))) __bf16;

// exp2 in one v_exp_f32 (inputs are pre-scaled by log2e)
#if __has_builtin(__builtin_amdgcn_exp2f)
#define EXP2(x) __builtin_amdgcn_exp2f(x)
#else
#define EXP2(x) __expf((x) * 0.6931471805599453f)
#endif

// lgkm-only barrier: does NOT drain vmcnt, so global_load_lds prefetch stays in
// flight across it (plain __syncthreads would emit s_waitcnt vmcnt(0)).
__device__ __forceinline__ void barrier_lgkm() {
    asm volatile("s_waitcnt lgkmcnt(0)\ns_barrier" ::: "memory");
}

// ---------------- async global->LDS staging (16B, XOR-swizzled chunks) ----------------
// Row f of 64 bf16 = 8 chunks of 8; LDS slot s of row f holds global chunk s^(f&7).
template<int FH>
__device__ __forceinline__ void stage_tile(const __bf16* __restrict__ hgp,
                                           __bf16* dst, int tid) {
#pragma unroll
    for (int it = 0; it < FH / 32; it++) {
        int c = tid + it * 256;
        int f = c >> 3, sl = c & 7;
        int g = sl ^ (f & 7);
        __builtin_amdgcn_global_load_lds(
            (const __attribute__((address_space(1))) void*)(hgp + (size_t)f * NN + g * 8),
            (__attribute__((address_space(3))) void*)(dst + (size_t)c * 8), 16, 0, 0);
    }
}

__device__ __forceinline__ void stage_g(const __bf16* __restrict__ base, int ldk,
                                        __bf16* dst, int tid) {
#pragma unroll
    for (int it = 0; it < 2; it++) {
        int c = tid + it * 256;
        int f = c >> 3, sl = c & 7;
        int g = sl ^ (f & 7);
        __builtin_amdgcn_global_load_lds(
            (const __attribute__((address_space(1))) void*)(base + (size_t)f * ldk + g * 8),
            (__attribute__((address_space(3))) void*)(dst + (size_t)c * 8), 16, 0, 0);
    }
}

// ---------------- adjacency -> bitmask ----------------
__global__ void pack_adj_kernel(const int* __restrict__ adj,
                                unsigned long long* __restrict__ bits) {
    int gw = (blockIdx.x * blockDim.x + threadIdx.x) >> 6;
    int lane = threadIdx.x & 63;
    int v = adj[(size_t)gw * 64 + lane];
    unsigned long long m = __ballot(v > 0);
    if (lane == 0) bits[gw] = m;
}

// ---------------- prepack: W_h -> Bt1[n=512][k=512] bf16, W_o -> Bt2[n=64][k=512] ----
__global__ void prepack_kernel(const float* __restrict__ W_h, const float* __restrict__ b_h,
                               const float* __restrict__ W_o,
                               __bf16* __restrict__ Bt1, float* __restrict__ biasp,
                               __bf16* __restrict__ Bt2) {
    int idx = blockIdx.x * 256 + threadIdx.x;   // 512*512
    {
        int n = idx >> 9, k = idx & 511;
        int h = n >> 7, f = n & 127;
        Bt1[idx] = (__bf16)W_h[(size_t)h * 512 * 128 + k * 128 + f];
    }
    if (idx < 64 * 512) {
        int n = idx >> 9, k = idx & 511;
        Bt2[idx] = (__bf16)W_o[k * 64 + n];
    }
    if (idx < 512) biasp[idx] = b_h[idx];
}

// ---------------- fp32 -> bf16 cast ----------------
__global__ void cast_bf16_kernel(const float* __restrict__ src, __bf16* __restrict__ dst) {
    int i = blockIdx.x * 256 + threadIdx.x;
    f32x4 v = *(const f32x4*)(src + (size_t)i * 4);
    bf16x4 o;
#pragma unroll
    for (int q = 0; q < 4; q++) o[q] = (__bf16)v[q];
    *(bf16x4*)(dst + (size_t)i * 4) = o;
}

// ---------------- fused bf16 MFMA GEMM ----------------
// Ht[col][row] = bf16( (A @ Bt^T)[row][col] + bias[col] )   (transposed store)
// s1[head][row] += sum_col h*a1[col]*LOG2E, s2 likewise (pre-scaled for exp2;
// lrelu is positively homogeneous so the scale commutes through it exactly).
__global__ __launch_bounds__(256) void gemm_fused_kernel(
    const __bf16* __restrict__ A, const __bf16* __restrict__ Bt,
    const float* __restrict__ bias,
    const float* __restrict__ a1, const float* __restrict__ a2,
    __bf16* __restrict__ Ht, float* __restrict__ s1, float* __restrict__ s2,
    int M, int N, int K)
{
    __shared__ __attribute__((aligned(16))) __bf16 As[2][64 * 64];
    __shared__ __attribute__((aligned(16))) __bf16 Bs[2][64 * 64];
    const int tid = threadIdx.x, w = tid >> 6, l = tid & 63, o = l >> 4, rl = l & 15;
    const int bm = blockIdx.y * 64, bn = blockIdx.x * 64;
    f32x4 acc[4] = {};
    stage_g(A + (size_t)bm * K, K, &As[0][0], tid);
    stage_g(Bt + (size_t)bn * K, K, &Bs[0][0], tid);
    const int KB = K / 64;
    for (int kb = 0; kb < KB; kb++) {
        int b = kb & 1;
        __syncthreads();
        if (kb + 1 < KB) {
            stage_g(A + (size_t)bm * K + (kb + 1) * 64, K, &As[b ^ 1][0], tid);
            stage_g(Bt + (size_t)bn * K + (kb + 1) * 64, K, &Bs[b ^ 1][0], tid);
        }
#pragma unroll
        for (int kt = 0; kt < 2; kt++) {
            int ra = w * 16 + rl;
            int cg = kt * 4 + o;
            bf16x8 af = *(const bf16x8*)(&As[b][(ra * 8 + (cg ^ (ra & 7))) * 8]);
#pragma unroll
            for (int nt = 0; nt < 4; nt++) {
                int rb = nt * 16 + rl;
                bf16x8 bfr = *(const bf16x8*)(&Bs[b][(rb * 8 + (cg ^ (rb & 7))) * 8]);
                acc[nt] = __builtin_amdgcn_mfma_f32_16x16x32_bf16(af, bfr, acc[nt], 0, 0, 0);
            }
        }
    }
    // epilogue: bias, transposed bf16 store, s1/s2 row-dot partials
    const int head = bn >> 7;
    const int row_base = bm + w * 16 + o * 4;
    float p1[4] = {0.f, 0.f, 0.f, 0.f}, p2[4] = {0.f, 0.f, 0.f, 0.f};
#pragma unroll
    for (int nt = 0; nt < 4; nt++) {
        int col = bn + nt * 16 + rl;
        float bv = bias[col];
        float a1v = a1[col] * LOG2E, a2v = a2[col] * LOG2E;
        bf16x4 hv;
#pragma unroll
        for (int r4 = 0; r4 < 4; r4++) {
            float h = acc[nt][r4] + bv;
            hv[r4] = (__bf16)h;
            p1[r4] += h * a1v;
            p2[r4] += h * a2v;
        }
        *(bf16x4*)(Ht + (size_t)col * M + row_base) = hv;
    }
#pragma unroll
    for (int r4 = 0; r4 < 4; r4++)
#pragma unroll
        for (int off = 1; off < 16; off <<= 1) {
            p1[r4] += __shfl_xor(p1[r4], off, 64);
            p2[r4] += __shfl_xor(p2[r4], off, 64);
        }
    if (rl == 0)
#pragma unroll
        for (int r4 = 0; r4 < 4; r4++) {
            atomicAdd(&s1[(size_t)head * M + row_base + r4], p1[r4]);
            atomicAdd(&s2[(size_t)head * M + row_base + r4], p2[r4]);
        }
}

// ---------------- global max of s2 per head ----------------
__global__ void smax_kernel(const float* __restrict__ s2, float* __restrict__ s2max) {
    const float* p = s2 + (size_t)blockIdx.x * NN;
    int t = threadIdx.x;
    float m = -INFINITY;
    for (int i = t; i < NN; i += 256) m = fmaxf(m, p[i]);
#pragma unroll
    for (int off = 1; off < 64; off <<= 1) m = fmaxf(m, __shfl_xor(m, off, 64));
    __shared__ float red[4];
    if ((t & 63) == 0) red[t >> 6] = m;
    __syncthreads();
    if (t == 0) s2max[blockIdx.x] = fmaxf(fmaxf(red[0], red[1]), fmaxf(red[2], red[3]));
}

// ---------------- MFMA attention, fragment-reuse, j-split partials, SW-pipelined ----
// 64-row blocks, 4 waves. Wave w produces P A-frags for rows [w*16, w*16+16)
// and consumes n-tiles [w*NTW*16, (w+1)*NTW*16) for ALL 4 m-tiles.
// SOFTWARE PIPELINE: the expensive produce chain (adj word + s2 loads +
// lrelu/exp2 + ps reduce) for tile jl+1 runs register-only INSIDE the B1->B2
// region of tile jl, interleaved by the scheduler with the 16 MFMAs — VALU
// and matrix pipes overlap, and the s2/adj L2 latency hides under the MFMAs.
// Only the plds *store* stays at the loop top (after B2), so the barrier
// discipline is identical to the proven structure.
// s1/s2 are pre-scaled by LOG2E -> p = exp2(e' - mrow') in one v_exp_f32.
template<int FH, int JSPLIT>
__global__ __launch_bounds__(256, 4) void attn_kernel(
    const __bf16* __restrict__ Htg,               // [heads*FH][NN]
    const unsigned long long* __restrict__ adj_bits,
    const float* __restrict__ s1_all, const float* __restrict__ s2_all,
    const float* __restrict__ s2max_all, const float* __restrict__ ab_all,
    __bf16* __restrict__ accp,                    // [JSPLIT][NN][ldo]
    float* __restrict__ lg,                       // [heads*JSPLIT][NN]
    int ldo)
{
    constexpr int NJT = NN / 64 / JSPLIT;
    constexpr int NTW = FH / 64;                  // n-tiles per wave (128->2, 64->1)
    const int head = blockIdx.y;
    const int js   = blockIdx.z;
    const int row0 = blockIdx.x * 64;
    const int jt0  = js * NJT;
    const int tid = threadIdx.x;
    const int w = tid >> 6, l = tid & 63, o = l >> 4, rl = l & 15;
    const int myrow = row0 + w * 16 + rl;         // producer row (mt = w)

    __shared__ __attribute__((aligned(16))) __bf16 hbuf[2][FH * 64];
    __shared__ __attribute__((aligned(16))) __bf16 plds[8 * 64 * 8];   // [mt*2+kt][lane]*8

    const float* s2 = s2_all + (size_t)head * NN;
    const __bf16* hg = Htg + (size_t)head * FH * NN;
    // s1/s2 already carry the LOG2E scale from the GEMM epilogue; ab scaled here.
    const float s1r = s1_all[(size_t)head * NN + myrow] + ab_all[head] * LOG2E;
    float mrow; { float x = s1r + s2max_all[head]; mrow = fmaxf(x, 0.2f * x); }
    float lacc = 0.f;
    f32x4 acc[4][NTW] = {};

    stage_tile<FH>(hg + (size_t)jt0 * 64, &hbuf[0][0], tid);

    // produce P fragments for tile jt into fr[2]; accumulates lacc.
    auto produce = [&](int jt, bf16x8* fr) {
        unsigned long long aw = adj_bits[(size_t)myrow * 64 + jt];
#pragma unroll
        for (int kt = 0; kt < 2; kt++) {
            unsigned int mbyte = (unsigned int)(aw >> ((kt * 4 + o) * 8)) & 0xFFu;
            const float* sp = s2 + jt * 64 + kt * 32 + o * 8;
            f32x4 sa = *(const f32x4*)(sp);
            f32x4 sb = *(const f32x4*)(sp + 4);
            float ps = 0.f;
#pragma unroll
            for (int qp = 0; qp < 4; qp++) {      // pairs -> bait v_pk_*_f32
                f32x2 sv;
                sv[0] = (qp < 2) ? sa[qp * 2]     : sb[qp * 2 - 4];
                sv[1] = (qp < 2) ? sa[qp * 2 + 1] : sb[qp * 2 - 3];
                f32x2 x = sv + s1r;
                f32x2 e = __builtin_elementwise_max(x, 0.2f * x) - mrow;
#pragma unroll
                for (int h2 = 0; h2 < 2; h2++) {
                    int q = qp * 2 + h2;
                    float t = ((mbyte >> q) & 1u) ? e[h2] : -1.0e20f;
                    float p = EXP2(t);            // 2^t; masked -> exact 0
                    fr[kt][q] = (__bf16)p;
                    ps += p;
                }
            }
            ps += __shfl_xor(ps, 16, 64);
            ps += __shfl_xor(ps, 32, 64);
            lacc += ps;
        }
    };

    bf16x8 freg[2];
    produce(jt0, freg);                           // prologue: tile 0 (overlaps DMA)

    for (int jl = 0; jl < NJT; jl++) {
        const int b = jl & 1;
        const int jt = jt0 + jl;
        // publish this tile's P fragments (plds free: previous B2 passed)
#pragma unroll
        for (int kt = 0; kt < 2; kt++)
            *(bf16x8*)(&plds[((w * 2 + kt) * 64 + l) * 8]) = freg[kt];
        __syncthreads();   // B1: plds visible; hbuf[b] DMA drained (vmcnt 0)
        if (jl + 1 < NJT)
            stage_tile<FH>(hg + (size_t)(jt + 1) * 64, &hbuf[b ^ 1][0], tid);
        // ---- B-frags once, reuse across all 4 m-tiles ----
        bf16x8 bfr[2][NTW];
#pragma unroll
        for (int kt = 0; kt < 2; kt++)
#pragma unroll
            for (int ntl = 0; ntl < NTW; ntl++) {
                int f = (w * NTW + ntl) * 16 + rl;
                int slot = (kt * 4 + o) ^ (rl & 7);
                bfr[kt][ntl] = *(const bf16x8*)(&hbuf[b][(f * 8 + slot) * 8]);
            }
        // ---- produce NEXT tile (register-only) — interleaves with the MFMAs ----
        bf16x8 fnext[2];
        if (jl + 1 < NJT) produce(jt + 1, fnext);
#pragma unroll
        for (int mt = 0; mt < 4; mt++)
#pragma unroll
            for (int kt = 0; kt < 2; kt++) {
                bf16x8 af = (mt == w) ? freg[kt]
                          : *(const bf16x8*)(&plds[((mt * 2 + kt) * 64 + l) * 8]);
#pragma unroll
                for (int ntl = 0; ntl < NTW; ntl++)
                    acc[mt][ntl] = __builtin_amdgcn_mfma_f32_16x16x32_bf16(
                        af, bfr[kt][ntl], acc[mt][ntl], 0, 0, 0);
            }
        barrier_lgkm();    // B2: plds reads done; DMA prefetch stays in flight
        if (jl + 1 < NJT) { freg[0] = fnext[0]; freg[1] = fnext[1]; }
    }
    // ---- epilogue: partial row-sums + unnormalized bf16 partial acc ----
    if (l < 16) lg[((size_t)head * JSPLIT + js) * NN + row0 + w * 16 + l] = lacc;
#pragma unroll
    for (int mt = 0; mt < 4; mt++)
#pragma unroll
        for (int ntl = 0; ntl < NTW; ntl++)
#pragma unroll
            for (int r4 = 0; r4 < 4; r4++) {
                int grow = row0 + mt * 16 + o * 4 + r4;
                int gcol = head * FH + (w * NTW + ntl) * 16 + rl;
                accp[((size_t)js * NN + grow) * ldo + gcol] = (__bf16)acc[mt][ntl][r4];
            }
}

// ---------------- combine layer-1 partials: normalize + elu -> bf16 [N][512] ----------------
__global__ void combine1_kernel(const __bf16* __restrict__ accp, const float* __restrict__ lg,
                                __bf16* __restrict__ outb) {
    int gid = blockIdx.x * 256 + threadIdx.x;        // N * 128
    int row = gid >> 7, c4 = (gid & 127) * 4;
    int head = c4 >> 7;
    float lsum = 0.f;
#pragma unroll
    for (int js = 0; js < 4; js++) lsum += lg[((size_t)head * 4 + js) * NN + row];
    float inv = lsum > 0.f ? 1.f / lsum : 0.f;
    float v[4] = {0.f, 0.f, 0.f, 0.f};
#pragma unroll
    for (int js = 0; js < 4; js++) {
        bf16x4 t = *(const bf16x4*)(accp + ((size_t)js * NN + row) * 512 + c4);
#pragma unroll
        for (int q = 0; q < 4; q++) v[q] += (float)t[q];
    }
    bf16x4 ob;
#pragma unroll
    for (int q = 0; q < 4; q++) {
        float x = v[q] * inv;
        x = x > 0.f ? x : __expf(x) - 1.f;
        ob[q] = (__bf16)x;
    }
    *(bf16x4*)(outb + (size_t)row * 512 + c4) = ob;
}

// ---------------- combine layer-2 partials + elu + log_softmax -> out ----------------
__global__ void combine2_kernel(const __bf16* __restrict__ accp, const float* __restrict__ lg,
                                float* __restrict__ out) {
    int row = (blockIdx.x * 256 + threadIdx.x) >> 6;
    int lane = threadIdx.x & 63;
    if (row >= NN) return;
    float lsum = 0.f, v = 0.f;
#pragma unroll
    for (int js = 0; js < 16; js++) {
        lsum += lg[(size_t)js * NN + row];
        v += (float)accp[((size_t)js * NN + row) * 64 + lane];
    }
    float inv = lsum > 0.f ? 1.f / lsum : 0.f;
    v *= inv;
    v = v > 0.f ? v : __expf(v) - 1.f;
    float m = v;
#pragma unroll
    for (int off = 1; off < 64; off <<= 1) m = fmaxf(m, __shfl_xor(m, off, 64));
    float ex = __expf(v - m);
    float s = ex;
#pragma unroll
    for (int off = 1; off < 64; off <<= 1) s += __shfl_xor(s, off, 64);
    out[(size_t)row * 64 + lane] = v - m - __logf(s);
}

extern "C" void kernel_launch(void* const* d_in, const int* in_sizes, int n_in,
                              void* d_out, int out_size, void* d_ws, size_t ws_size,
                              hipStream_t stream) {
    const float* X    = (const float*)d_in[0];
    const int*   adj  = (const int*)d_in[1];
    const float* W_h  = (const float*)d_in[2];
    const float* b_h  = (const float*)d_in[3];
    const float* a1_h = (const float*)d_in[4];
    const float* a2_h = (const float*)d_in[5];
    const float* ab_h = (const float*)d_in[6];
    const float* W_o  = (const float*)d_in[7];
    const float* b_o  = (const float*)d_in[8];
    const float* a1_o = (const float*)d_in[9];
    const float* a2_o = (const float*)d_in[10];
    const float* ab_o = (const float*)d_in[11];
    float* out = (float*)d_out;

    char* ws = (char*)d_ws;
    auto alloc = [&](size_t bytes) {
        char* p = ws; ws += (bytes + 255) & ~(size_t)255; return p;
    };
    unsigned long long* adj_bits = (unsigned long long*)alloc((size_t)NN * 64 * 8); // 2 MB
    __bf16* Bt1    = (__bf16*)alloc((size_t)512 * 512 * 2);     // 512 KB
    float*  biasp  = (float*)alloc(512 * 4);
    __bf16* Bt2    = (__bf16*)alloc((size_t)64 * 512 * 2);      // 64 KB
    __bf16* Xb     = (__bf16*)alloc((size_t)NN * 512 * 2);      // 4 MB
    float*  s1h    = (float*)alloc((size_t)4 * NN * 4);         // |-- contiguous,
    float*  s2h    = (float*)alloc((size_t)4 * NN * 4);         // |   one memset
    float*  s1o    = (float*)alloc((size_t)NN * 4);             // |   (160 KB)
    float*  s2o    = (float*)alloc((size_t)NN * 4);             // |
    float*  s2maxh = (float*)alloc(4 * 4);
    float*  s2maxo = (float*)alloc(4);
    __bf16* Htg    = (__bf16*)alloc((size_t)512 * NN * 2);      // 4 MB
    __bf16* accp1  = (__bf16*)alloc((size_t)4 * NN * 512 * 2);  // 16 MB
    float*  lg1    = (float*)alloc((size_t)16 * NN * 4);        // 256 KB
    __bf16* outhb  = (__bf16*)alloc((size_t)NN * 512 * 2);      // 4 MB
    __bf16* Ht2    = (__bf16*)alloc((size_t)64 * NN * 2);       // 512 KB
    __bf16* accp2  = (__bf16*)alloc((size_t)16 * NN * 64 * 2);  // 8 MB
    float*  lg2    = (float*)alloc((size_t)16 * NN * 4);        // 256 KB  (~40 MB)

    // 0. zero the atomic s1/s2 accumulators (contiguous block)
    hipMemsetAsync(s1h, 0, (size_t)(4 + 4 + 1 + 1) * NN * 4, stream);
    // 1. adjacency -> bitmasks (single read of the 67 MB int32 matrix)
    pack_adj_kernel<<<(NN * 64) / 4, 256, 0, stream>>>(adj, adj_bits);
    // 2. prepack weights (bf16, [n][k])
    prepack_kernel<<<1024, 256, 0, stream>>>(W_h, b_h, W_o, Bt1, biasp, Bt2);
    // 3. X -> bf16
    cast_bf16_kernel<<<(NN * 512 / 4) / 256, 256, 0, stream>>>(X, Xb);
    // 4. layer-1 GEMM fused: Htg (transposed bf16) + s1h/s2h atomics (LOG2E-scaled)
    gemm_fused_kernel<<<dim3(8, 64), 256, 0, stream>>>(
        Xb, Bt1, biasp, a1_h, a2_h, Htg, s1h, s2h, NN, 512, 512);
    // 5. per-head global s2 max
    smax_kernel<<<4, 256, 0, stream>>>(s2h, s2maxh);
    // 6. attention layer 1 partials (4 heads x 4 j-splits)
    attn_kernel<128, 4><<<dim3(NN / 64, 4, 4), 256, 0, stream>>>(
        Htg, adj_bits, s1h, s2h, s2maxh, ab_h, accp1, lg1, 512);
    // 7. combine -> elu -> bf16 concat features [N][512]
    combine1_kernel<<<(NN * 128) / 256, 256, 0, stream>>>(accp1, lg1, outhb);
    // 8. layer-2 GEMM fused: Ht2 (transposed bf16) + s1o/s2o atomics (LOG2E-scaled)
    gemm_fused_kernel<<<dim3(1, 64), 256, 0, stream>>>(
        outhb, Bt2, b_o, a1_o, a2_o, Ht2, s1o, s2o, NN, 64, 512);
    // 9. s2 max (output layer)
    smax_kernel<<<1, 256, 0, stream>>>(s2o, s2maxo);
    // 10. attention layer 2 partials (16 j-splits)
    attn_kernel<64, 16><<<dim3(NN / 64, 1, 16), 256, 0, stream>>>(
        Ht2, adj_bits, s1o, s2o, s2maxo, ab_o, accp2, lg2, 64);
    // 11. combine + elu + log_softmax -> out
    combine2_kernel<<<(NN * 64) / 256, 256, 0, stream>>>(accp2, lg2, out);
}